// Round 17
// baseline (547.133 us; speedup 1.0000x reference)
//
#include <hip/hip_runtime.h>

#define E 1024
#define H 4096
#define NLAYER 24
#define V 50277
#define LN_EPS 1e-5f

typedef unsigned long long u64;

struct Params {
  const float* emb;   const float* ln0_w; const float* ln0_b;
  const float* ln1_w; const float* ln1_b;
  const float* tmk;   const float* tmv;   const float* tmr;
  const float* tf;    const float* td;
  const float* kw;    const float* vw;    const float* rw;  const float* ow;
  const float* ln2_w; const float* ln2_b;
  const float* ftmk;  const float* ftmr;
  const float* fkw;   const float* fvw;   const float* frw;
  const float* lnow;  const float* lnob;  const float* headw;
  const float* st;    const int* tok;
  float* out; float* ws;
};

// ---- tagged 8-byte dataflow handoff (relaxed agent scope) ----
__device__ __forceinline__ void stg_tag(u64* p, float v, unsigned tag) {
  u64 w = ((u64)__float_as_uint(v) << 32) | (u64)tag;
  __hip_atomic_store(p, w, __ATOMIC_RELAXED, __HIP_MEMORY_SCOPE_AGENT);
}
__device__ __forceinline__ u64 ld_tag(const u64* p) {
  return __hip_atomic_load(p, __ATOMIC_RELAXED, __HIP_MEMORY_SCOPE_AGENT);
}
__device__ __forceinline__ float poll_tag(const u64* p, unsigned tag) {
  u64 w = ld_tag(p);
  while ((unsigned)w != tag) { __builtin_amdgcn_s_sleep(1); w = ld_tag(p); }
  return __uint_as_float((unsigned)(w >> 32));
}
#define TAGWAIT(w, ptr, tagv) \
  while ((unsigned)(w) != (tagv)) { __builtin_amdgcn_s_sleep(1); (w) = ld_tag(ptr); }
__device__ __forceinline__ float tagval(u64 w) {
  return __uint_as_float((unsigned)(w >> 32));
}

__device__ __forceinline__ void wait_pf() {
  asm volatile("s_waitcnt vmcnt(0)" ::: "memory");
}

// zero-VGPR global->LDS DMA: 64 lanes x 16 B = 1 KB per call.
__device__ __forceinline__ void gload_lds16(const float* g, float* l) {
  __builtin_amdgcn_global_load_lds(
      (const __attribute__((address_space(1))) unsigned int*)(g),
      (__attribute__((address_space(3))) unsigned int*)(l), 16, 0, 0);
}
__device__ __forceinline__ void pf_row4k(const float* row, float* dst, int lane) {
#pragma unroll
  for (int c = 0; c < 4; ++c)
    gload_lds16(row + c * 256 + lane * 4, dst + c * 256);
}

__device__ __forceinline__ float warp_sum(float v) {
#pragma unroll
  for (int off = 32; off; off >>= 1) v += __shfl_down(v, off);
  return v;
}

__device__ __forceinline__ float dot4(float4 a, float4 b) {
  return a.x * b.x + a.y * b.y + a.z * b.z + a.w * b.w;
}

__device__ __forceinline__ float dotlds(const float* wrow, const float* vec, int lane) {
  const float4* w4 = (const float4*)wrow;
  const float4* v4 = (const float4*)vec;
  float acc = 0.f;
#pragma unroll
  for (int p = 0; p < 4; ++p)
    acc += dot4(w4[lane + p * 64], v4[lane + p * 64]);
  return warp_sum(acc);
}

// single-sync LN stats, 16-wave (1024-thread) block, 1 elem/thread
__device__ __forceinline__ float2 ln_stats_w16(float v, float* red) {
  float a = v, b = v * v;
#pragma unroll
  for (int off = 32; off; off >>= 1) { a += __shfl_xor(a, off); b += __shfl_xor(b, off); }
  const int wid = threadIdx.x >> 6, lane = threadIdx.x & 63;
  if (lane == 0) { red[2 * wid] = a; red[2 * wid + 1] = b; }
  __syncthreads();
  float s1 = 0.f, s2 = 0.f;
  const float2* r2 = (const float2*)red;
#pragma unroll
  for (int j = 0; j < 16; ++j) { float2 t = r2[j]; s1 += t.x; s2 += t.y; }
  float m = s1 * (1.f / E);
  return make_float2(m, s2 * (1.f / E) - m * m);
}

// single-sync LN stats, 8-wave (512-thread) block, 2 elems/thread pre-summed
__device__ __forceinline__ float2 ln_stats_w8(float a, float b, float* red) {
#pragma unroll
  for (int off = 32; off; off >>= 1) { a += __shfl_xor(a, off); b += __shfl_xor(b, off); }
  const int wid = threadIdx.x >> 6, lane = threadIdx.x & 63;
  if (lane == 0) { red[2 * wid] = a; red[2 * wid + 1] = b; }
  __syncthreads();
  float s1 = 0.f, s2 = 0.f;
  const float2* r2 = (const float2*)red;
#pragma unroll
  for (int j = 0; j < 8; ++j) { float2 t = r2[j]; s1 += t.x; s2 += t.y; }
  float m = s1 * (1.f / E);
  return make_float2(m, s2 * (1.f / E) - m * m);
}

// ================================================================
// Kernel A: 256 blocks x 1024 threads (R15, proven 545 us)
// LDS: 160000 B
// ================================================================
#define A_R1O    0
#define A_R2O    16384
#define A_POOLO  32768
#define A_SXO    36864
#define A_SSXO   37888
#define A_FXRO   38912
#define A_REDO   39936
#define A_PARTO  39968
#define A_PART2O 39984
#define A_SMEMF  40000

__global__ __launch_bounds__(1024, 1) void rwkv_kernel_1024(Params p) {
  const int tid = threadIdx.x, bid = blockIdx.x;
  const int lane = tid & 63, wid = tid >> 6;

  extern __shared__ float smem[];
  float* r1     = smem + A_R1O;
  float* r2     = smem + A_R2O;
  float* pool   = smem + A_POOLO;
  float* s_x    = smem + A_SXO;
  float* s_sx   = smem + A_SSXO;
  float* s_fxr  = smem + A_FXRO;
  float* s_red  = smem + A_REDO;
  float* s_part = smem + A_PARTO;
  float* s_part2= smem + A_PART2O;

  u64* tws = (u64*)p.ws;
  u64* tk  = tws;             // [2][E]
  u64* tv  = tws + 2 * E;
  u64* tr  = tws + 4 * E;
  u64* tsx = tws + 6 * E;
  u64* tx  = tws + 8 * E;
  u64* tfk = tws + 10 * E;    // [2][H]

  float* out_st = p.out + V;
  const int token = p.tok[0];

  const bool hasA = wid < 12;
  const int rA = bid * 12 + wid;
  const int matA = rA >> 10, rmA = rA & (E - 1);
  const int rloc = wid >> 2, kc = wid & 3;
  const int rowO = bid * 4 + rloc;
  float* wA = r1 + wid * 1024;
  float* wD = r2 + rloc * 4096 + kc * 1024;

  if (hasA) {
    const float* W = (matA == 0 ? p.kw : matA == 1 ? p.vw : p.rw) + (size_t)rmA * E;
    pf_row4k(W, wA, lane);
  }

  {
    float v = p.emb[(size_t)token * E + tid];
    float2 mv = ln_stats_w16(v, s_red);
    s_x[tid] = (v - mv.x) / sqrtf(mv.y + LN_EPS) * p.ln0_w[tid] + p.ln0_b[tid];
  }

  for (int l = 0; l < NLAYER; ++l) {
    const float* stl = p.st + (size_t)5 * l * E;
    float* ostl = out_st + (size_t)5 * l * E;
    const int par = l & 1;
    const unsigned tg = (unsigned)(l + 1);

    // ---- Phase A ----
    float l1w = p.ln1_w[l * E + tid], l1b = p.ln1_b[l * E + tid];
    float ax = stl[E + tid];
    float ta = p.tmk[l * E + tid], tb = p.tmv[l * E + tid], tc = p.tmr[l * E + tid];
    float xv_;
    if (l > 0) { xv_ = poll_tag(&tx[par * E + tid], (unsigned)l); s_x[tid] = xv_; }
    else       { xv_ = s_x[tid]; }
    {
      float2 mv = ln_stats_w16(xv_, s_red);
      float xn = (xv_ - mv.x) / sqrtf(mv.y + LN_EPS) * l1w + l1b;
      pool[tid]        = xn * ta + ax * (1.f - ta);
      pool[1024 + tid] = xn * tb + ax * (1.f - tb);
      pool[2048 + tid] = xn * tc + ax * (1.f - tc);
      if (bid == 0) ostl[E + tid] = xn;
    }
    __syncthreads();
    wait_pf();
    if (hasA) {
      float d = dotlds(wA, pool + matA * 1024, lane);
      if (lane == 0) {
        u64* dst = (matA == 0 ? tk : matA == 1 ? tv : tr) + par * E + rmA;
        stg_tag(dst, matA == 2 ? 1.f / (1.f + expf(-d)) : d, tg);
      }
    }

    // ---- Phase B ----
    {
      float aav = stl[2 * E + tid], bbv = stl[3 * E + tid], ppv = stl[4 * E + tid];
      float tfv = p.tf[l * E + tid], tdv = p.td[l * E + tid];
      float4 wow = ((const float4*)(p.ow + (size_t)l * E * E + (size_t)rowO * E + kc * 256))[lane];
      pf_row4k(p.fkw + (size_t)l * H * E + (size_t)(bid * 16 + wid) * E, wA, lane);
      const u64 *bk = tk + par * E + tid, *bv = tv + par * E + tid, *br = tr + par * E + tid;
      u64 wk = ld_tag(bk), wv = ld_tag(bv), wr = ld_tag(br);
      TAGWAIT(wk, bk, tg); TAGWAIT(wv, bv, tg); TAGWAIT(wr, br, tg);
      float kk = tagval(wk), vv = tagval(wv), rr = tagval(wr);
      float wwv = tfv + kk;
      float pm = fmaxf(ppv, wwv);
      float e1 = expf(ppv - pm), e2 = expf(wwv - pm);
      float a = e1 * aav + e2 * vv, b = e1 * bbv + e2;
      pool[3072 + tid] = rr * a / b;
      float ww2 = ppv + tdv;
      float p2 = fmaxf(ww2, kk);
      float f1 = expf(ww2 - p2), f2 = expf(kk - p2);
      if (bid == 0) {
        ostl[2 * E + tid] = f1 * aav + f2 * vv;
        ostl[3 * E + tid] = f1 * bbv + f2;
        ostl[4 * E + tid] = p2;
      }
      __syncthreads();
      const float4* v4 = (const float4*)(pool + 3072 + kc * 256);
      float acc = warp_sum(dot4(wow, v4[lane]));
      if (lane == 0) s_part[wid] = acc;
    }
    __syncthreads();
    if (tid < 4) {
      float dsum = s_part[tid * 4] + s_part[tid * 4 + 1] +
                   s_part[tid * 4 + 2] + s_part[tid * 4 + 3];
      stg_tag(&tsx[par * E + bid * 4 + tid], s_x[bid * 4 + tid] + dsum, tg);
    }

    // ---- Phase C ----
    {
      float l2w = p.ln2_w[l * E + tid], l2b = p.ln2_b[l * E + tid];
      float fx = stl[tid];
      float fa = p.ftmk[l * E + tid], fb = p.ftmr[l * E + tid];
      float4 wfr = ((const float4*)(p.frw + (size_t)l * E * E + (size_t)rowO * E + kc * 256))[lane];
      pf_row4k(p.fvw + (size_t)l * E * H + (size_t)rowO * H + kc * 1024, wD, lane);
      float sxv = poll_tag(&tsx[par * E + tid], tg);
      s_sx[tid] = sxv;
      float2 mv = ln_stats_w16(sxv, s_red);
      float xn2 = (sxv - mv.x) / sqrtf(mv.y + LN_EPS) * l2w + l2b;
      pool[tid]  = xn2 * fa + fx * (1.f - fa);
      s_fxr[tid] = xn2 * fb + fx * (1.f - fb);
      if (bid == 0) ostl[tid] = xn2;
      __syncthreads();
      float d = dotlds(wA, pool, lane);
      if (lane == 0) { float t = fmaxf(d, 0.f); stg_tag(&tfk[par * H + bid * 16 + wid], t * t, tg); }
      const float4* f4 = (const float4*)(s_fxr + kc * 256);
      float fp = warp_sum(dot4(wfr, f4[lane]));
      if (lane == 0) s_part2[wid] = fp;
    }

    // ---- Phase D ----
    if (l + 1 < NLAYER && hasA) {
      const float* W = (matA == 0 ? p.kw : matA == 1 ? p.vw : p.rw) +
                       (size_t)(l + 1) * E * E + (size_t)rmA * E;
      pf_row4k(W, wA, lane);
    }
    __syncthreads();
    {
      const u64* base = tfk + par * H;
      u64 w0 = ld_tag(base + tid);
      u64 w1 = ld_tag(base + tid + 1024);
      u64 w2 = ld_tag(base + tid + 2048);
      u64 w3 = ld_tag(base + tid + 3072);
      TAGWAIT(w0, base + tid, tg);        TAGWAIT(w1, base + tid + 1024, tg);
      TAGWAIT(w2, base + tid + 2048, tg); TAGWAIT(w3, base + tid + 3072, tg);
      pool[tid]        = tagval(w0);
      pool[tid + 1024] = tagval(w1);
      pool[tid + 2048] = tagval(w2);
      pool[tid + 3072] = tagval(w3);
    }
    __syncthreads();
    {
      const float4* v4 = (const float4*)(pool + kc * 1024);
      const float4* w4 = (const float4*)wD;
      float acc = 0.f;
#pragma unroll
      for (int pc = 0; pc < 4; ++pc)
        acc += dot4(w4[lane + pc * 64], v4[lane + pc * 64]);
      acc = warp_sum(acc);
      if (lane == 0) s_part[wid] = acc;
    }
    __syncthreads();
    if (tid < 4) {
      float dsum = s_part[tid * 4] + s_part[tid * 4 + 1] +
                   s_part[tid * 4 + 2] + s_part[tid * 4 + 3];
      float frs  = s_part2[tid * 4] + s_part2[tid * 4 + 1] +
                   s_part2[tid * 4 + 2] + s_part2[tid * 4 + 3];
      float fr = 1.f / (1.f + expf(-frs));
      stg_tag(&tx[((l + 1) & 1) * E + bid * 4 + tid],
              s_sx[bid * 4 + tid] + fr * dsum, tg);
    }
  }

  // ---- Head ----
  {
    float xv_ = poll_tag(&tx[(NLAYER & 1) * E + tid], (unsigned)NLAYER);
    float2 mv = ln_stats_w16(xv_, s_red);
    pool[tid] = (xv_ - mv.x) / sqrtf(mv.y + LN_EPS) * p.lnow[tid] + p.lnob[tid];
  }
  __syncthreads();
  {
    const int gw = bid * 16 + wid;
    const float4* v4 = (const float4*)pool;
    float4 x0 = v4[lane], x1 = v4[lane + 64], x2 = v4[lane + 128], x3 = v4[lane + 192];
    int row = gw;
    for (; row + 12288 < V; row += 16384) {
      const float4* W0 = (const float4*)(p.headw + (size_t)row * E);
      const float4* W1 = (const float4*)(p.headw + (size_t)(row + 4096) * E);
      const float4* W2 = (const float4*)(p.headw + (size_t)(row + 8192) * E);
      const float4* W3 = (const float4*)(p.headw + (size_t)(row + 12288) * E);
      float a0 = 0.f, a1 = 0.f, a2 = 0.f, a3 = 0.f;
      a0 += dot4(W0[lane], x0) + dot4(W0[lane + 64], x1) + dot4(W0[lane + 128], x2) + dot4(W0[lane + 192], x3);
      a1 += dot4(W1[lane], x0) + dot4(W1[lane + 64], x1) + dot4(W1[lane + 128], x2) + dot4(W1[lane + 192], x3);
      a2 += dot4(W2[lane], x0) + dot4(W2[lane + 64], x1) + dot4(W2[lane + 128], x2) + dot4(W2[lane + 192], x3);
      a3 += dot4(W3[lane], x0) + dot4(W3[lane + 64], x1) + dot4(W3[lane + 128], x2) + dot4(W3[lane + 192], x3);
      a0 = warp_sum(a0); a1 = warp_sum(a1); a2 = warp_sum(a2); a3 = warp_sum(a3);
      if (lane == 0) {
        p.out[row] = a0; p.out[row + 4096] = a1;
        p.out[row + 8192] = a2; p.out[row + 12288] = a3;
      }
    }
    for (; row < V; row += 4096) {
      const float4* W0 = (const float4*)(p.headw + (size_t)row * E);
      float a0 = dot4(W0[lane], x0) + dot4(W0[lane + 64], x1) +
                 dot4(W0[lane + 128], x2) + dot4(W0[lane + 192], x3);
      a0 = warp_sum(a0);
      if (lane == 0) p.out[row] = a0;
    }
  }
}

// ================================================================
// Kernel B: 512 blocks x 512 threads (2 blocks/CU attempt)
// LDS: 57600 B
// ================================================================
#define B_R1O    0
#define B_POOLO  8192
#define B_SXO    12288
#define B_SSXO   13312
#define B_REDO   14336
#define B_PARTO  14368
#define B_PART2O 14384
#define B_SMEMF  14400

__global__ __launch_bounds__(512, 4) void rwkv_kernel_512(Params p) {
  const int tid = threadIdx.x, bid = blockIdx.x;
  const int lane = tid & 63, wid = tid >> 6;
  const int e0 = tid, e1 = tid + 512;

  extern __shared__ float smem[];
  float* r1     = smem + B_R1O;
  float* pool   = smem + B_POOLO;
  float* s_x    = smem + B_SXO;
  float* s_sx   = smem + B_SSXO;
  float* s_red  = smem + B_REDO;
  float* s_part = smem + B_PARTO;
  float* s_part2= smem + B_PART2O;

  u64* tws = (u64*)p.ws;
  u64* tk  = tws;
  u64* tv  = tws + 2 * E;
  u64* tr  = tws + 4 * E;
  u64* tsx = tws + 6 * E;
  u64* tx  = tws + 8 * E;
  u64* tfk = tws + 10 * E;

  float* out_st = p.out + V;
  const int token = p.tok[0];

  const bool hasA = wid < 6;
  const int rA = bid * 6 + wid;
  const int matA = rA >> 10, rmA = rA & (E - 1);
  const int rloc = wid >> 2, kc = wid & 3;
  const int rowO = bid * 2 + rloc;
  float* wA = r1 + wid * 1024;

  if (hasA) {
    const float* W = (matA == 0 ? p.kw : matA == 1 ? p.vw : p.rw) + (size_t)rmA * E;
    pf_row4k(W, wA, lane);
  } else {
    pf_row4k(p.ow + (size_t)(bid * 2 + wid - 6) * E, wA, lane);
  }

  {
    float v0 = p.emb[(size_t)token * E + e0];
    float v1 = p.emb[(size_t)token * E + e1];
    float2 mv = ln_stats_w8(v0 + v1, v0 * v0 + v1 * v1, s_red);
    float is = 1.f / sqrtf(mv.y + LN_EPS);
    s_x[e0] = (v0 - mv.x) * is * p.ln0_w[e0] + p.ln0_b[e0];
    s_x[e1] = (v1 - mv.x) * is * p.ln0_w[e1] + p.ln0_b[e1];
  }

  for (int l = 0; l < NLAYER; ++l) {
    const float* stl = p.st + (size_t)5 * l * E;
    float* ostl = out_st + (size_t)5 * l * E;
    const int par = l & 1;
    const unsigned tg = (unsigned)(l + 1);

    // ---- Phase A ----
    float l1w0 = p.ln1_w[l * E + e0], l1b0 = p.ln1_b[l * E + e0];
    float l1w1 = p.ln1_w[l * E + e1], l1b1 = p.ln1_b[l * E + e1];
    float ax0 = stl[E + e0], ax1 = stl[E + e1];
    float ta0 = p.tmk[l * E + e0], tb0 = p.tmv[l * E + e0], tc0 = p.tmr[l * E + e0];
    float ta1 = p.tmk[l * E + e1], tb1 = p.tmv[l * E + e1], tc1 = p.tmr[l * E + e1];
    float xv0, xv1;
    if (l > 0) {
      const u64 *a0 = &tx[par * E + e0], *a1 = &tx[par * E + e1];
      u64 w0 = ld_tag(a0), w1 = ld_tag(a1);
      TAGWAIT(w0, a0, (unsigned)l); TAGWAIT(w1, a1, (unsigned)l);
      xv0 = tagval(w0); xv1 = tagval(w1);
      s_x[e0] = xv0; s_x[e1] = xv1;
    } else { xv0 = s_x[e0]; xv1 = s_x[e1]; }
    {
      float2 mv = ln_stats_w8(xv0 + xv1, xv0 * xv0 + xv1 * xv1, s_red);
      float is = 1.f / sqrtf(mv.y + LN_EPS);
      float xn0 = (xv0 - mv.x) * is * l1w0 + l1b0;
      float xn1 = (xv1 - mv.x) * is * l1w1 + l1b1;
      pool[e0]        = xn0 * ta0 + ax0 * (1.f - ta0);
      pool[e1]        = xn1 * ta1 + ax1 * (1.f - ta1);
      pool[1024 + e0] = xn0 * tb0 + ax0 * (1.f - tb0);
      pool[1024 + e1] = xn1 * tb1 + ax1 * (1.f - tb1);
      pool[2048 + e0] = xn0 * tc0 + ax0 * (1.f - tc0);
      pool[2048 + e1] = xn1 * tc1 + ax1 * (1.f - tc1);
      if (bid == 0) { ostl[E + e0] = xn0; ostl[E + e1] = xn1; }
    }
    __syncthreads();
    wait_pf();
    if (hasA) {
      float d = dotlds(wA, pool + matA * 1024, lane);
      if (lane == 0) {
        u64* dst = (matA == 0 ? tk : matA == 1 ? tv : tr) + par * E + rmA;
        stg_tag(dst, matA == 2 ? 1.f / (1.f + expf(-d)) : d, tg);
      }
    }

    // ---- Phase B ----
    {
      float aav0 = stl[2 * E + e0], bbv0 = stl[3 * E + e0], ppv0 = stl[4 * E + e0];
      float aav1 = stl[2 * E + e1], bbv1 = stl[3 * E + e1], ppv1 = stl[4 * E + e1];
      float tfv0 = p.tf[l * E + e0], tdv0 = p.td[l * E + e0];
      float tfv1 = p.tf[l * E + e1], tdv1 = p.td[l * E + e1];
      float4 wow = ((const float4*)(p.ow + (size_t)l * E * E + (size_t)rowO * E + kc * 256))[lane];
      if (wid < 6)
        pf_row4k(p.fkw + (size_t)l * H * E + (size_t)(bid * 8 + wid) * E, wA, lane);
      const u64 *pk0 = &tk[par * E + e0], *pv0 = &tv[par * E + e0], *pr0 = &tr[par * E + e0];
      const u64 *pk1 = &tk[par * E + e1], *pv1 = &tv[par * E + e1], *pr1 = &tr[par * E + e1];
      u64 qk0 = ld_tag(pk0), qv0 = ld_tag(pv0), qr0 = ld_tag(pr0);
      u64 qk1 = ld_tag(pk1), qv1 = ld_tag(pv1), qr1 = ld_tag(pr1);
      TAGWAIT(qk0, pk0, tg); TAGWAIT(qv0, pv0, tg); TAGWAIT(qr0, pr0, tg);
      TAGWAIT(qk1, pk1, tg); TAGWAIT(qv1, pv1, tg); TAGWAIT(qr1, pr1, tg);
      float kk0 = tagval(qk0), vv0 = tagval(qv0), rr0 = tagval(qr0);
      float kk1 = tagval(qk1), vv1 = tagval(qv1), rr1 = tagval(qr1);
      {
        float wwv = tfv0 + kk0;
        float pm = fmaxf(ppv0, wwv);
        float ee1 = expf(ppv0 - pm), ee2 = expf(wwv - pm);
        float a = ee1 * aav0 + ee2 * vv0, b = ee1 * bbv0 + ee2;
        pool[3072 + e0] = rr0 * a / b;
        float ww2 = ppv0 + tdv0;
        float p2 = fmaxf(ww2, kk0);
        float f1 = expf(ww2 - p2), f2 = expf(kk0 - p2);
        if (bid == 0) {
          ostl[2 * E + e0] = f1 * aav0 + f2 * vv0;
          ostl[3 * E + e0] = f1 * bbv0 + f2;
          ostl[4 * E + e0] = p2;
        }
      }
      {
        float wwv = tfv1 + kk1;
        float pm = fmaxf(ppv1, wwv);
        float ee1 = expf(ppv1 - pm), ee2 = expf(wwv - pm);
        float a = ee1 * aav1 + ee2 * vv1, b = ee1 * bbv1 + ee2;
        pool[3072 + e1] = rr1 * a / b;
        float ww2 = ppv1 + tdv1;
        float p2 = fmaxf(ww2, kk1);
        float f1 = expf(ww2 - p2), f2 = expf(kk1 - p2);
        if (bid == 0) {
          ostl[2 * E + e1] = f1 * aav1 + f2 * vv1;
          ostl[3 * E + e1] = f1 * bbv1 + f2;
          ostl[4 * E + e1] = p2;
        }
      }
      __syncthreads();
      const float4* v4 = (const float4*)(pool + 3072 + kc * 256);
      float acc = warp_sum(dot4(wow, v4[lane]));
      if (lane == 0) s_part[wid] = acc;
    }
    __syncthreads();
    if (wid >= 6)
      pf_row4k(p.fkw + (size_t)l * H * E + (size_t)(bid * 8 + wid) * E, wA, lane);
    if (tid < 2) {
      float dsum = s_part[tid * 4] + s_part[tid * 4 + 1] +
                   s_part[tid * 4 + 2] + s_part[tid * 4 + 3];
      stg_tag(&tsx[par * E + bid * 2 + tid], s_x[bid * 2 + tid] + dsum, tg);
    }

    // ---- Phase C ----
    {
      float l2w0 = p.ln2_w[l * E + e0], l2b0 = p.ln2_b[l * E + e0];
      float l2w1 = p.ln2_w[l * E + e1], l2b1 = p.ln2_b[l * E + e1];
      float fx0 = stl[e0], fx1 = stl[e1];
      float fa0 = p.ftmk[l * E + e0], fb0 = p.ftmr[l * E + e0];
      float fa1 = p.ftmk[l * E + e1], fb1 = p.ftmr[l * E + e1];
      float4 wfr = ((const float4*)(p.frw + (size_t)l * E * E + (size_t)rowO * E + kc * 256))[lane];
      const u64 *s0 = &tsx[par * E + e0], *s1 = &tsx[par * E + e1];
      u64 w0 = ld_tag(s0), w1 = ld_tag(s1);
      TAGWAIT(w0, s0, tg); TAGWAIT(w1, s1, tg);
      float sxv0 = tagval(w0), sxv1 = tagval(w1);
      s_sx[e0] = sxv0; s_sx[e1] = sxv1;
      float2 mv = ln_stats_w8(sxv0 + sxv1, sxv0 * sxv0 + sxv1 * sxv1, s_red);
      float is = 1.f / sqrtf(mv.y + LN_EPS);
      float xn20 = (sxv0 - mv.x) * is * l2w0 + l2b0;
      float xn21 = (sxv1 - mv.x) * is * l2w1 + l2b1;
      pool[e0]        = xn20 * fa0 + fx0 * (1.f - fa0);
      pool[e1]        = xn21 * fa1 + fx1 * (1.f - fa1);
      pool[1024 + e0] = xn20 * fb0 + fx0 * (1.f - fb0);
      pool[1024 + e1] = xn21 * fb1 + fx1 * (1.f - fb1);
      if (bid == 0) { ostl[e0] = xn20; ostl[e1] = xn21; }
      __syncthreads();
      float d = dotlds(wA, pool, lane);
      if (lane == 0) { float t = fmaxf(d, 0.f); stg_tag(&tfk[par * H + bid * 8 + wid], t * t, tg); }
      const float4* f4 = (const float4*)(pool + 1024 + kc * 256);
      float fp = warp_sum(dot4(wfr, f4[lane]));
      if (lane == 0) s_part2[wid] = fp;
    }

    // ---- Phase D ----
    if (l + 1 < NLAYER) {
      if (hasA) {
        const float* W = (matA == 0 ? p.kw : matA == 1 ? p.vw : p.rw) +
                         (size_t)(l + 1) * E * E + (size_t)rmA * E;
        pf_row4k(W, wA, lane);
      } else {
        pf_row4k(p.ow + (size_t)(l + 1) * E * E + (size_t)(bid * 2 + wid - 6) * E, wA, lane);
      }
    }
    __syncthreads();
    {
      const float4* Wf = (const float4*)(p.fvw + (size_t)l * E * H + (size_t)rowO * H + kc * 1024);
      float4 f0 = Wf[lane], f1 = Wf[lane + 64], f2 = Wf[lane + 128], f3 = Wf[lane + 192];
      const u64* base = tfk + par * H;
      u64 q0 = ld_tag(base + tid);
      u64 q1 = ld_tag(base + tid + 512);
      u64 q2 = ld_tag(base + tid + 1024);
      u64 q3 = ld_tag(base + tid + 1536);
      u64 q4 = ld_tag(base + tid + 2048);
      u64 q5 = ld_tag(base + tid + 2560);
      u64 q6 = ld_tag(base + tid + 3072);
      u64 q7 = ld_tag(base + tid + 3584);
      TAGWAIT(q0, base + tid, tg);        TAGWAIT(q1, base + tid + 512, tg);
      TAGWAIT(q2, base + tid + 1024, tg); TAGWAIT(q3, base + tid + 1536, tg);
      TAGWAIT(q4, base + tid + 2048, tg); TAGWAIT(q5, base + tid + 2560, tg);
      TAGWAIT(q6, base + tid + 3072, tg); TAGWAIT(q7, base + tid + 3584, tg);
      pool[tid]        = tagval(q0); pool[tid + 512]  = tagval(q1);
      pool[tid + 1024] = tagval(q2); pool[tid + 1536] = tagval(q3);
      pool[tid + 2048] = tagval(q4); pool[tid + 2560] = tagval(q5);
      pool[tid + 3072] = tagval(q6); pool[tid + 3584] = tagval(q7);
      __syncthreads();
      const float4* v4 = (const float4*)(pool + kc * 1024);
      float acc = dot4(f0, v4[lane]) + dot4(f1, v4[lane + 64]) +
                  dot4(f2, v4[lane + 128]) + dot4(f3, v4[lane + 192]);
      acc = warp_sum(acc);
      if (lane == 0) s_part[wid] = acc;
    }
    __syncthreads();
    if (tid < 2) {
      float dsum = s_part[tid * 4] + s_part[tid * 4 + 1] +
                   s_part[tid * 4 + 2] + s_part[tid * 4 + 3];
      float frs  = s_part2[tid * 4] + s_part2[tid * 4 + 1] +
                   s_part2[tid * 4 + 2] + s_part2[tid * 4 + 3];
      float fr = 1.f / (1.f + expf(-frs));
      stg_tag(&tx[((l + 1) & 1) * E + bid * 2 + tid],
              s_sx[bid * 2 + tid] + fr * dsum, tg);
    }
  }

  // ---- Head ----
  {
    const u64 *a0 = &tx[(NLAYER & 1) * E + e0], *a1 = &tx[(NLAYER & 1) * E + e1];
    u64 w0 = ld_tag(a0), w1 = ld_tag(a1);
    TAGWAIT(w0, a0, (unsigned)NLAYER); TAGWAIT(w1, a1, (unsigned)NLAYER);
    float xv0 = tagval(w0), xv1 = tagval(w1);
    float2 mv = ln_stats_w8(xv0 + xv1, xv0 * xv0 + xv1 * xv1, s_red);
    float is = 1.f / sqrtf(mv.y + LN_EPS);
    pool[e0] = (xv0 - mv.x) * is * p.lnow[e0] + p.lnob[e0];
    pool[e1] = (xv1 - mv.x) * is * p.lnow[e1] + p.lnob[e1];
  }
  __syncthreads();
  {
    const int gw = bid * 8 + wid;
    const float4* v4 = (const float4*)pool;
    float4 x0 = v4[lane], x1 = v4[lane + 64], x2 = v4[lane + 128], x3 = v4[lane + 192];
    int row = gw;
    for (; row + 12288 < V; row += 16384) {
      const float4* W0 = (const float4*)(p.headw + (size_t)row * E);
      const float4* W1 = (const float4*)(p.headw + (size_t)(row + 4096) * E);
      const float4* W2 = (const float4*)(p.headw + (size_t)(row + 8192) * E);
      const float4* W3 = (const float4*)(p.headw + (size_t)(row + 12288) * E);
      float a0 = 0.f, a1 = 0.f, a2 = 0.f, a3 = 0.f;
      a0 += dot4(W0[lane], x0) + dot4(W0[lane + 64], x1) + dot4(W0[lane + 128], x2) + dot4(W0[lane + 192], x3);
      a1 += dot4(W1[lane], x0) + dot4(W1[lane + 64], x1) + dot4(W1[lane + 128], x2) + dot4(W1[lane + 192], x3);
      a2 += dot4(W2[lane], x0) + dot4(W2[lane + 64], x1) + dot4(W2[lane + 128], x2) + dot4(W2[lane + 192], x3);
      a3 += dot4(W3[lane], x0) + dot4(W3[lane + 64], x1) + dot4(W3[lane + 128], x2) + dot4(W3[lane + 192], x3);
      a0 = warp_sum(a0); a1 = warp_sum(a1); a2 = warp_sum(a2); a3 = warp_sum(a3);
      if (lane == 0) {
        p.out[row] = a0; p.out[row + 4096] = a1;
        p.out[row + 8192] = a2; p.out[row + 12288] = a3;
      }
    }
    for (; row < V; row += 4096) {
      const float4* W0 = (const float4*)(p.headw + (size_t)row * E);
      float a0 = dot4(W0[lane], x0) + dot4(W0[lane + 64], x1) +
                 dot4(W0[lane + 128], x2) + dot4(W0[lane + 192], x3);
      a0 = warp_sum(a0);
      if (lane == 0) p.out[row] = a0;
    }
  }
}

extern "C" void kernel_launch(void* const* d_in, const int* in_sizes, int n_in,
                              void* d_out, int out_size, void* d_ws, size_t ws_size,
                              hipStream_t stream) {
  Params p;
  p.emb   = (const float*)d_in[0];
  p.ln0_w = (const float*)d_in[1];
  p.ln0_b = (const float*)d_in[2];
  p.ln1_w = (const float*)d_in[3];
  p.ln1_b = (const float*)d_in[4];
  p.tmk   = (const float*)d_in[5];
  p.tmv   = (const float*)d_in[6];
  p.tmr   = (const float*)d_in[7];
  p.tf    = (const float*)d_in[8];
  p.td    = (const float*)d_in[9];
  p.kw    = (const float*)d_in[10];
  p.vw    = (const float*)d_in[11];
  p.rw    = (const float*)d_in[12];
  p.ow    = (const float*)d_in[13];
  p.ln2_w = (const float*)d_in[14];
  p.ln2_b = (const float*)d_in[15];
  p.ftmk  = (const float*)d_in[16];
  p.ftmr  = (const float*)d_in[17];
  p.fkw   = (const float*)d_in[18];
  p.fvw   = (const float*)d_in[19];
  p.frw   = (const float*)d_in[20];
  p.lnow  = (const float*)d_in[21];
  p.lnob  = (const float*)d_in[22];
  p.headw = (const float*)d_in[23];
  if (in_sizes[24] == 1) {
    p.tok = (const int*)d_in[24];
    p.st  = (const float*)d_in[25];
  } else {
    p.st  = (const float*)d_in[24];
    p.tok = (const int*)d_in[25];
  }
  p.out   = (float*)d_out;
  p.ws    = (float*)d_ws;

  // zero ALL tag words each launch (graph node): (10E + 2H) u64 = 147456 B
  hipMemsetAsync(d_ws, 0, (10 * E + 2 * H) * sizeof(unsigned long long), stream);

  // Occupancy-gated selection (deterministic, capture-safe query):
  // prefer the 2-blocks/CU 512x512 kernel only if the runtime can actually
  // co-schedule 2 blocks per CU; otherwise use the proven 256x1024 kernel.
  int maxb = 0;
  hipError_t qerr = hipOccupancyMaxActiveBlocksPerMultiprocessor(
      &maxb, (const void*)rwkv_kernel_512, 512, (size_t)B_SMEMF * sizeof(float));
  void* args[] = { &p };
  if (qerr == hipSuccess && maxb >= 2) {
    hipError_t lerr = hipLaunchCooperativeKernel((const void*)rwkv_kernel_512,
                                                 dim3(512), dim3(512), args,
                                                 B_SMEMF * sizeof(float), stream);
    if (lerr == hipSuccess) return;
  }
  hipLaunchCooperativeKernel((const void*)rwkv_kernel_1024, dim3(256), dim3(1024),
                             args, A_SMEMF * sizeof(float), stream);
}